// Round 1
// baseline (498.206 us; speedup 1.0000x reference)
//
#include <hip/hip_runtime.h>
#include <cstdint>
#include <cstddef>

#define NN 50000
#define NE 800000
#define GRAPHS 512

// ----------------- counting sort: build dst-CSR -----------------
__global__ __launch_bounds__(256) void hist_kernel(const int* __restrict__ dst,
                                                   int* __restrict__ deg) {
  int e = blockIdx.x * 256 + threadIdx.x;
  if (e < NE) atomicAdd(&deg[dst[e]], 1);
}

__global__ __launch_bounds__(1024) void scan_kernel(const int* __restrict__ deg,
                                                    int* __restrict__ row_start,
                                                    int* __restrict__ cursor) {
  __shared__ int sd[1024];
  const int t = threadIdx.x;
  const int chunk = 49;                       // 1024*49 = 50176 >= 50000
  int base = t * chunk;
  int end = base + chunk; if (end > NN) end = NN;
  int partial = 0;
  if (base < NN) for (int i = base; i < end; ++i) partial += deg[i];
  sd[t] = partial;
  __syncthreads();
  for (int off = 1; off < 1024; off <<= 1) {
    int v = (t >= off) ? sd[t - off] : 0;
    __syncthreads();
    sd[t] += v;
    __syncthreads();
  }
  int run = sd[t] - partial;                  // exclusive offset for this chunk
  if (base < NN) {
    for (int i = base; i < end; ++i) {
      row_start[i] = run; cursor[i] = run; run += deg[i];
    }
  }
  if (t == 0) row_start[NN] = sd[1023];
}

__global__ __launch_bounds__(256) void scatter_kernel(const int* __restrict__ src,
                                                      const int* __restrict__ dst,
                                                      int* __restrict__ cursor,
                                                      int* __restrict__ ssrc) {
  int e = blockIdx.x * 256 + threadIdx.x;
  if (e < NE) {
    int p = atomicAdd(&cursor[dst[e]], 1);
    ssrc[p] = src[e];
  }
}

// ----------------- dual skinny GEMM -----------------
// blockIdx.y == 0: hW  = act(h) @ W_rel            (goes to aggregation)
// blockIdx.y == 1: buf = act(h) @ W_root + b_rel   (root term + bias, agg adds onto it)
// 64 nodes x 64 cols per block, 256 threads, 4x4 register tile per thread.
template<int K, bool RELU>
__global__ __launch_bounds__(256) void gemm_half(const float* __restrict__ h,
    const float* __restrict__ Wrel, const float* __restrict__ Wroot,
    const float* __restrict__ brel,
    float* __restrict__ hW, float* __restrict__ buf) {
  constexpr int HP = K + 4;                   // pad -> 2-way (free) LDS banking
  __shared__ float hs[64 * HP];
  __shared__ float ws[64 * 64];               // one 64-row K-chunk of W
  const int t = threadIdx.x;
  const int row0 = blockIdx.x * 64;
  const bool root = (blockIdx.y != 0);
  const float* __restrict__ W = root ? Wroot : Wrel;

  // stage 64 x K tile of h (apply input ReLU here)
  for (int idx = t; idx < 64 * (K / 4); idx += 256) {
    int n = idx / (K / 4), kq = idx % (K / 4);
    int node = row0 + n;
    float4 v = make_float4(0.f, 0.f, 0.f, 0.f);
    if (node < NN) v = *(const float4*)&h[(size_t)node * K + kq * 4];
    if (RELU) {
      v.x = fmaxf(v.x, 0.f); v.y = fmaxf(v.y, 0.f);
      v.z = fmaxf(v.z, 0.f); v.w = fmaxf(v.w, 0.f);
    }
    *(float4*)&hs[n * HP + kq * 4] = v;
  }

  const int tx = t & 15, ty = t >> 4;
  const int c0 = tx * 4, n0 = ty * 4;
  float acc[4][4];
  #pragma unroll
  for (int i = 0; i < 4; ++i)
    #pragma unroll
    for (int j = 0; j < 4; ++j) acc[i][j] = 0.f;

  for (int kb = 0; kb < K; kb += 64) {
    __syncthreads();                          // also covers hs staging on 1st iter
    for (int idx = t; idx < 64 * 16; idx += 256) {
      int k = idx >> 4, cq = idx & 15;
      *(float4*)&ws[k * 64 + cq * 4] = *(const float4*)&W[(size_t)(kb + k) * 64 + cq * 4];
    }
    __syncthreads();
    for (int k = 0; k < 64; k += 4) {
      float4 hv[4], wv[4];
      #pragma unroll
      for (int i = 0; i < 4; ++i) hv[i] = *(const float4*)&hs[(n0 + i) * HP + kb + k];
      #pragma unroll
      for (int kk = 0; kk < 4; ++kk) wv[kk] = *(const float4*)&ws[(k + kk) * 64 + c0];
      #pragma unroll
      for (int kk = 0; kk < 4; ++kk) {
        #pragma unroll
        for (int i = 0; i < 4; ++i) {
          float a = ((const float*)&hv[i])[kk];
          acc[i][0] += a * wv[kk].x;
          acc[i][1] += a * wv[kk].y;
          acc[i][2] += a * wv[kk].z;
          acc[i][3] += a * wv[kk].w;
        }
      }
    }
  }

  float4 bb = make_float4(0.f, 0.f, 0.f, 0.f);
  if (root) bb = *(const float4*)&brel[c0];
  float* __restrict__ outp = root ? buf : hW;
  #pragma unroll
  for (int i = 0; i < 4; ++i) {
    int node = row0 + n0 + i;
    if (node >= NN) continue;
    float4 o = make_float4(acc[i][0] + bb.x, acc[i][1] + bb.y,
                           acc[i][2] + bb.z, acc[i][3] + bb.w);
    *(float4*)&outp[(size_t)node * 64 + c0] = o;
  }
}

// ----------------- CSR aggregation: buf[n] += sum_{e in CSR[n]} hW[src_e] --------
__global__ __launch_bounds__(256) void aggregate_kernel(const float* __restrict__ hW,
    const int* __restrict__ row_start, const int* __restrict__ ssrc,
    float* __restrict__ buf) {
  int tid = blockIdx.x * 256 + threadIdx.x;
  int node = tid >> 4, c = tid & 15;
  if (node >= NN) return;
  float4 acc = *(const float4*)&buf[(size_t)node * 64 + c * 4];
  int s0 = row_start[node], s1 = row_start[node + 1];
  for (int e = s0; e < s1; ++e) {
    int s = ssrc[e];
    float4 v = *(const float4*)&hW[(size_t)s * 64 + c * 4];
    acc.x += v.x; acc.y += v.y; acc.z += v.z; acc.w += v.w;
  }
  *(float4*)&buf[(size_t)node * 64 + c * 4] = acc;
}

// ----------------- mean pool (ReLU on load) -----------------
__global__ __launch_bounds__(256) void pool_kernel(const float* __restrict__ buf,
    const int* __restrict__ batch, float* __restrict__ pooled,
    float* __restrict__ cnt) {
  int tid = blockIdx.x * 256 + threadIdx.x;
  int node = tid >> 4, c = tid & 15;
  if (node >= NN) return;
  int g = batch[node];
  float4 v = *(const float4*)&buf[(size_t)node * 64 + c * 4];
  v.x = fmaxf(v.x, 0.f); v.y = fmaxf(v.y, 0.f);
  v.z = fmaxf(v.z, 0.f); v.w = fmaxf(v.w, 0.f);
  unsafeAtomicAdd(&pooled[g * 64 + c * 4 + 0], v.x);
  unsafeAtomicAdd(&pooled[g * 64 + c * 4 + 1], v.y);
  unsafeAtomicAdd(&pooled[g * 64 + c * 4 + 2], v.z);
  unsafeAtomicAdd(&pooled[g * 64 + c * 4 + 3], v.w);
  if (c == 0) unsafeAtomicAdd(&cnt[g], 1.0f);
}

// ----------------- MLP head: one 64-thread block per graph -----------------
__global__ __launch_bounds__(64) void head_kernel(const float* __restrict__ pooled,
    const float* __restrict__ cnt,
    const float* __restrict__ Wfc1, const float* __restrict__ bfc1,
    const float* __restrict__ Wfc2, const float* __restrict__ bfc2,
    float* __restrict__ out) {
  __shared__ float m[64];
  __shared__ float h1[32];
  int g = blockIdx.x, l = threadIdx.x;
  float c = fmaxf(cnt[g], 1.0f);
  m[l] = pooled[g * 64 + l] / c;
  __syncthreads();
  if (l < 32) {
    float a = bfc1[l];
    for (int k = 0; k < 64; ++k) a += m[k] * Wfc1[k * 32 + l];
    h1[l] = fmaxf(a, 0.f);
  }
  __syncthreads();
  if (l == 0) {
    float o = bfc2[0];
    for (int j = 0; j < 32; ++j) o += h1[j] * Wfc2[j];
    out[g] = o;
  }
}

extern "C" void kernel_launch(void* const* d_in, const int* in_sizes, int n_in,
                              void* d_out, int out_size, void* d_ws, size_t ws_size,
                              hipStream_t stream) {
  const float* x      = (const float*)d_in[0];
  const int*   ei     = (const int*)d_in[1];
  const int*   batch  = (const int*)d_in[2];
  const float* Wrel1  = (const float*)d_in[3];
  const float* brel1  = (const float*)d_in[4];
  const float* Wroot1 = (const float*)d_in[5];
  const float* Wrel2  = (const float*)d_in[6];
  const float* brel2  = (const float*)d_in[7];
  const float* Wroot2 = (const float*)d_in[8];
  const float* Wrel3  = (const float*)d_in[9];
  const float* brel3  = (const float*)d_in[10];
  const float* Wroot3 = (const float*)d_in[11];
  const float* Wfc1   = (const float*)d_in[12];
  const float* bfc1   = (const float*)d_in[13];
  const float* Wfc2   = (const float*)d_in[14];
  const float* bfc2   = (const float*)d_in[15];
  const int* src = ei;
  const int* dst = ei + NE;

  char* w = (char*)d_ws;
  auto alloc = [&](size_t bytes) -> char* {
    char* p = w; w += (bytes + 255) & ~(size_t)255; return p;
  };
  float* hW     = (float*)alloc((size_t)NN * 64 * 4);
  float* bufA   = (float*)alloc((size_t)NN * 64 * 4);
  float* bufB   = (float*)alloc((size_t)NN * 64 * 4);
  int*   deg    = (int*)alloc((size_t)NN * 4);
  int*   rs     = (int*)alloc((size_t)(NN + 1) * 4);
  int*   cur    = (int*)alloc((size_t)(NN + 1) * 4);
  int*   ssrc   = (int*)alloc((size_t)NE * 4);
  float* pooled = (float*)alloc((size_t)(GRAPHS * 64 + GRAPHS) * 4);
  float* cnt    = pooled + GRAPHS * 64;

  hipMemsetAsync(deg, 0, (size_t)NN * 4, stream);
  hipMemsetAsync(pooled, 0, (size_t)(GRAPHS * 64 + GRAPHS) * 4, stream);

  hist_kernel<<<NE / 256, 256, 0, stream>>>(dst, deg);
  scan_kernel<<<1, 1024, 0, stream>>>(deg, rs, cur);
  scatter_kernel<<<NE / 256, 256, 0, stream>>>(src, dst, cur, ssrc);

  dim3 ggrid((NN + 63) / 64, 2);
  const int agrid = (NN * 16 + 255) / 256;  // 3125

  gemm_half<128, false><<<ggrid, 256, 0, stream>>>(x, Wrel1, Wroot1, brel1, hW, bufA);
  aggregate_kernel<<<agrid, 256, 0, stream>>>(hW, rs, ssrc, bufA);

  gemm_half<64, true><<<ggrid, 256, 0, stream>>>(bufA, Wrel2, Wroot2, brel2, hW, bufB);
  aggregate_kernel<<<agrid, 256, 0, stream>>>(hW, rs, ssrc, bufB);

  gemm_half<64, true><<<ggrid, 256, 0, stream>>>(bufB, Wrel3, Wroot3, brel3, hW, bufA);
  aggregate_kernel<<<agrid, 256, 0, stream>>>(hW, rs, ssrc, bufA);

  pool_kernel<<<agrid, 256, 0, stream>>>(bufA, batch, pooled, cnt);
  head_kernel<<<GRAPHS, 64, 0, stream>>>(pooled, cnt, Wfc1, bfc1, Wfc2, bfc2,
                                         (float*)d_out);
}

// Round 2
// 400.483 us; speedup vs baseline: 1.2440x; 1.2440x over previous
//
#include <hip/hip_runtime.h>
#include <cstdint>
#include <cstddef>

#define NN 50000
#define NE 800000
#define GRAPHS 512

// ----------------- counting sort: build dst-CSR -----------------
__global__ __launch_bounds__(256) void hist_kernel(const int* __restrict__ dst,
                                                   int* __restrict__ deg) {
  int e = blockIdx.x * 256 + threadIdx.x;
  if (e < NE) atomicAdd(&deg[dst[e]], 1);
}

__global__ __launch_bounds__(1024) void scan_kernel(const int* __restrict__ deg,
                                                    int* __restrict__ row_start,
                                                    int* __restrict__ cursor) {
  __shared__ int sd[1024];
  const int t = threadIdx.x;
  const int chunk = 49;                       // 1024*49 = 50176 >= 50000
  int base = t * chunk;
  int end = base + chunk; if (end > NN) end = NN;
  int partial = 0;
  if (base < NN) for (int i = base; i < end; ++i) partial += deg[i];
  sd[t] = partial;
  __syncthreads();
  for (int off = 1; off < 1024; off <<= 1) {
    int v = (t >= off) ? sd[t - off] : 0;
    __syncthreads();
    sd[t] += v;
    __syncthreads();
  }
  int run = sd[t] - partial;                  // exclusive offset for this chunk
  if (base < NN) {
    for (int i = base; i < end; ++i) {
      row_start[i] = run; cursor[i] = run; run += deg[i];
    }
  }
  if (t == 0) row_start[NN] = sd[1023];
}

__global__ __launch_bounds__(256) void scatter_kernel(const int* __restrict__ src,
                                                      const int* __restrict__ dst,
                                                      int* __restrict__ cursor,
                                                      int* __restrict__ ssrc) {
  int e = blockIdx.x * 256 + threadIdx.x;
  if (e < NE) {
    int p = atomicAdd(&cursor[dst[e]], 1);
    ssrc[p] = src[e];
  }
}

// ----------------- graph boundaries (batch is sorted) -----------------
__global__ __launch_bounds__(256) void bounds_kernel(const int* __restrict__ batch,
                                                     int* __restrict__ gstart) {
  int g = blockIdx.x * 256 + threadIdx.x;
  if (g > GRAPHS) return;
  int lo = 0, hi = NN;                        // lower_bound: first i with batch[i] >= g
  while (lo < hi) {
    int mid = (lo + hi) >> 1;
    if (batch[mid] < g) lo = mid + 1; else hi = mid;
  }
  gstart[g] = lo;
}

// ----------------- dual skinny GEMM -----------------
// blockIdx.y == 0: hW  = act(h) @ W_rel            (goes to aggregation)
// blockIdx.y == 1: buf = act(h) @ W_root + b_rel   (root term + bias, agg adds onto it)
// 64 nodes x 64 cols per block, 256 threads, 4x4 register tile per thread.
template<int K, bool RELU>
__global__ __launch_bounds__(256) void gemm_half(const float* __restrict__ h,
    const float* __restrict__ Wrel, const float* __restrict__ Wroot,
    const float* __restrict__ brel,
    float* __restrict__ hW, float* __restrict__ buf) {
  constexpr int HP = K + 4;                   // pad -> 2-way (free) LDS banking
  __shared__ float hs[64 * HP];
  __shared__ float ws[64 * 64];               // one 64-row K-chunk of W
  const int t = threadIdx.x;
  const int row0 = blockIdx.x * 64;
  const bool root = (blockIdx.y != 0);
  const float* __restrict__ W = root ? Wroot : Wrel;

  // stage 64 x K tile of h (apply input ReLU here)
  for (int idx = t; idx < 64 * (K / 4); idx += 256) {
    int n = idx / (K / 4), kq = idx % (K / 4);
    int node = row0 + n;
    float4 v = make_float4(0.f, 0.f, 0.f, 0.f);
    if (node < NN) v = *(const float4*)&h[(size_t)node * K + kq * 4];
    if (RELU) {
      v.x = fmaxf(v.x, 0.f); v.y = fmaxf(v.y, 0.f);
      v.z = fmaxf(v.z, 0.f); v.w = fmaxf(v.w, 0.f);
    }
    *(float4*)&hs[n * HP + kq * 4] = v;
  }

  const int tx = t & 15, ty = t >> 4;
  const int c0 = tx * 4, n0 = ty * 4;
  float acc[4][4];
  #pragma unroll
  for (int i = 0; i < 4; ++i)
    #pragma unroll
    for (int j = 0; j < 4; ++j) acc[i][j] = 0.f;

  for (int kb = 0; kb < K; kb += 64) {
    __syncthreads();                          // also covers hs staging on 1st iter
    for (int idx = t; idx < 64 * 16; idx += 256) {
      int k = idx >> 4, cq = idx & 15;
      *(float4*)&ws[k * 64 + cq * 4] = *(const float4*)&W[(size_t)(kb + k) * 64 + cq * 4];
    }
    __syncthreads();
    for (int k = 0; k < 64; k += 4) {
      float4 hv[4], wv[4];
      #pragma unroll
      for (int i = 0; i < 4; ++i) hv[i] = *(const float4*)&hs[(n0 + i) * HP + kb + k];
      #pragma unroll
      for (int kk = 0; kk < 4; ++kk) wv[kk] = *(const float4*)&ws[(k + kk) * 64 + c0];
      #pragma unroll
      for (int kk = 0; kk < 4; ++kk) {
        #pragma unroll
        for (int i = 0; i < 4; ++i) {
          float a = ((const float*)&hv[i])[kk];
          acc[i][0] += a * wv[kk].x;
          acc[i][1] += a * wv[kk].y;
          acc[i][2] += a * wv[kk].z;
          acc[i][3] += a * wv[kk].w;
        }
      }
    }
  }

  float4 bb = make_float4(0.f, 0.f, 0.f, 0.f);
  if (root) bb = *(const float4*)&brel[c0];
  float* __restrict__ outp = root ? buf : hW;
  #pragma unroll
  for (int i = 0; i < 4; ++i) {
    int node = row0 + n0 + i;
    if (node >= NN) continue;
    float4 o = make_float4(acc[i][0] + bb.x, acc[i][1] + bb.y,
                           acc[i][2] + bb.z, acc[i][3] + bb.w);
    *(float4*)&outp[(size_t)node * 64 + c0] = o;
  }
}

// ----------------- CSR aggregation: buf[n] += sum_{e in CSR[n]} hW[src_e] --------
__global__ __launch_bounds__(256) void aggregate_kernel(const float* __restrict__ hW,
    const int* __restrict__ row_start, const int* __restrict__ ssrc,
    float* __restrict__ buf) {
  int tid = blockIdx.x * 256 + threadIdx.x;
  int node = tid >> 4, c = tid & 15;
  if (node >= NN) return;
  float4 acc = *(const float4*)&buf[(size_t)node * 64 + c * 4];
  int s0 = row_start[node], s1 = row_start[node + 1];
  for (int e = s0; e < s1; ++e) {
    int s = ssrc[e];
    float4 v = *(const float4*)&hW[(size_t)s * 64 + c * 4];
    acc.x += v.x; acc.y += v.y; acc.z += v.z; acc.w += v.w;
  }
  *(float4*)&buf[(size_t)node * 64 + c * 4] = acc;
}

// ----------------- fused mean-pool + MLP head: one block per graph -----------------
__global__ __launch_bounds__(256) void pool_head_kernel(const float* __restrict__ buf,
    const int* __restrict__ gstart,
    const float* __restrict__ Wfc1, const float* __restrict__ bfc1,
    const float* __restrict__ Wfc2, const float* __restrict__ bfc2,
    float* __restrict__ out) {
  __shared__ float ps[4][64];
  __shared__ float m[64];
  __shared__ float h1[32];
  const int g = blockIdx.x, t = threadIdx.x;
  const int c = t & 63, w = t >> 6;
  const int s0 = gstart[g], s1 = gstart[g + 1];
  float acc = 0.f;
  for (int i = s0 + w; i < s1; i += 4)
    acc += fmaxf(buf[(size_t)i * 64 + c], 0.f);
  ps[w][c] = acc;
  __syncthreads();
  if (t < 64) {
    float n = (float)(s1 - s0);
    m[t] = (ps[0][t] + ps[1][t] + ps[2][t] + ps[3][t]) / fmaxf(n, 1.0f);
  }
  __syncthreads();
  if (t < 32) {
    float a = bfc1[t];
    #pragma unroll
    for (int k = 0; k < 64; ++k) a += m[k] * Wfc1[k * 32 + t];
    h1[t] = fmaxf(a, 0.f);
  }
  __syncthreads();
  if (t == 0) {
    float o = bfc2[0];
    #pragma unroll
    for (int j = 0; j < 32; ++j) o += h1[j] * Wfc2[j];
    out[g] = o;
  }
}

extern "C" void kernel_launch(void* const* d_in, const int* in_sizes, int n_in,
                              void* d_out, int out_size, void* d_ws, size_t ws_size,
                              hipStream_t stream) {
  const float* x      = (const float*)d_in[0];
  const int*   ei     = (const int*)d_in[1];
  const int*   batch  = (const int*)d_in[2];
  const float* Wrel1  = (const float*)d_in[3];
  const float* brel1  = (const float*)d_in[4];
  const float* Wroot1 = (const float*)d_in[5];
  const float* Wrel2  = (const float*)d_in[6];
  const float* brel2  = (const float*)d_in[7];
  const float* Wroot2 = (const float*)d_in[8];
  const float* Wrel3  = (const float*)d_in[9];
  const float* brel3  = (const float*)d_in[10];
  const float* Wroot3 = (const float*)d_in[11];
  const float* Wfc1   = (const float*)d_in[12];
  const float* bfc1   = (const float*)d_in[13];
  const float* Wfc2   = (const float*)d_in[14];
  const float* bfc2   = (const float*)d_in[15];
  const int* src = ei;
  const int* dst = ei + NE;

  char* w = (char*)d_ws;
  auto alloc = [&](size_t bytes) -> char* {
    char* p = w; w += (bytes + 255) & ~(size_t)255; return p;
  };
  float* hW     = (float*)alloc((size_t)NN * 64 * 4);
  float* bufA   = (float*)alloc((size_t)NN * 64 * 4);
  float* bufB   = (float*)alloc((size_t)NN * 64 * 4);
  int*   deg    = (int*)alloc((size_t)NN * 4);
  int*   rs     = (int*)alloc((size_t)(NN + 1) * 4);
  int*   cur    = (int*)alloc((size_t)(NN + 1) * 4);
  int*   ssrc   = (int*)alloc((size_t)NE * 4);
  int*   gstart = (int*)alloc((size_t)(GRAPHS + 1) * 4);

  hipMemsetAsync(deg, 0, (size_t)NN * 4, stream);

  hist_kernel<<<NE / 256, 256, 0, stream>>>(dst, deg);
  scan_kernel<<<1, 1024, 0, stream>>>(deg, rs, cur);
  scatter_kernel<<<NE / 256, 256, 0, stream>>>(src, dst, cur, ssrc);
  bounds_kernel<<<(GRAPHS + 1 + 255) / 256, 256, 0, stream>>>(batch, gstart);

  dim3 ggrid((NN + 63) / 64, 2);
  const int agrid = (NN * 16 + 255) / 256;  // 3125

  gemm_half<128, false><<<ggrid, 256, 0, stream>>>(x, Wrel1, Wroot1, brel1, hW, bufA);
  aggregate_kernel<<<agrid, 256, 0, stream>>>(hW, rs, ssrc, bufA);

  gemm_half<64, true><<<ggrid, 256, 0, stream>>>(bufA, Wrel2, Wroot2, brel2, hW, bufB);
  aggregate_kernel<<<agrid, 256, 0, stream>>>(hW, rs, ssrc, bufB);

  gemm_half<64, true><<<ggrid, 256, 0, stream>>>(bufB, Wrel3, Wroot3, brel3, hW, bufA);
  aggregate_kernel<<<agrid, 256, 0, stream>>>(hW, rs, ssrc, bufA);

  pool_head_kernel<<<GRAPHS, 256, 0, stream>>>(bufA, gstart, Wfc1, bfc1, Wfc2, bfc2,
                                               (float*)d_out);
}

// Round 3
// 301.801 us; speedup vs baseline: 1.6508x; 1.3270x over previous
//
#include <hip/hip_runtime.h>
#include <cstdint>
#include <cstddef>

#define NN 50000
#define NE 800000
#define GRAPHS 512
#define NB 196                                // ceil(50000/256)

// ----------------- counting sort: build dst-CSR -----------------
__global__ __launch_bounds__(256) void hist_kernel(const int* __restrict__ dst,
                                                   int* __restrict__ deg) {
  int e = blockIdx.x * 256 + threadIdx.x;
  if (e < NE) atomicAdd(&deg[dst[e]], 1);
}

// phase 1: per-block sums of deg
__global__ __launch_bounds__(256) void reduce_kernel(const int* __restrict__ deg,
                                                     int* __restrict__ partials) {
  __shared__ int sd[256];
  const int t = threadIdx.x;
  int i = blockIdx.x * 256 + t;
  sd[t] = (i < NN) ? deg[i] : 0;
  __syncthreads();
  for (int off = 128; off > 0; off >>= 1) {
    if (t < off) sd[t] += sd[t + off];
    __syncthreads();
  }
  if (t == 0) partials[blockIdx.x] = sd[0];
}

// phase 2: exclusive scan of the 196 partials (single block)
__global__ __launch_bounds__(256) void scan_partials_kernel(int* __restrict__ partials,
                                                            int* __restrict__ row_start) {
  __shared__ int sd[256];
  const int t = threadIdx.x;
  int v = (t < NB) ? partials[t] : 0;
  sd[t] = v;
  __syncthreads();
  for (int off = 1; off < 256; off <<= 1) {
    int u = (t >= off) ? sd[t - off] : 0;
    __syncthreads();
    sd[t] += u;
    __syncthreads();
  }
  if (t < NB) partials[t] = sd[t] - v;        // exclusive block offset
  if (t == 255) row_start[NN] = sd[255];      // grand total (= NE)
}

// phase 3: per-block exclusive scan + block offset -> row_start, cursor
__global__ __launch_bounds__(256) void scan_write_kernel(const int* __restrict__ deg,
                                                         const int* __restrict__ partials,
                                                         int* __restrict__ row_start,
                                                         int* __restrict__ cursor) {
  __shared__ int sd[256];
  const int t = threadIdx.x;
  int i = blockIdx.x * 256 + t;
  int v = (i < NN) ? deg[i] : 0;
  sd[t] = v;
  __syncthreads();
  for (int off = 1; off < 256; off <<= 1) {
    int u = (t >= off) ? sd[t - off] : 0;
    __syncthreads();
    sd[t] += u;
    __syncthreads();
  }
  int ex = sd[t] - v + partials[blockIdx.x];
  if (i < NN) { row_start[i] = ex; cursor[i] = ex; }
}

__global__ __launch_bounds__(256) void scatter_kernel(const int* __restrict__ src,
                                                      const int* __restrict__ dst,
                                                      int* __restrict__ cursor,
                                                      int* __restrict__ ssrc) {
  int e = blockIdx.x * 256 + threadIdx.x;
  if (e < NE) {
    int p = atomicAdd(&cursor[dst[e]], 1);
    ssrc[p] = src[e];
  }
}

// ----------------- graph boundaries (batch is sorted) -----------------
__global__ __launch_bounds__(256) void bounds_kernel(const int* __restrict__ batch,
                                                     int* __restrict__ gstart) {
  int g = blockIdx.x * 256 + threadIdx.x;
  if (g > GRAPHS) return;
  int lo = 0, hi = NN;                        // lower_bound: first i with batch[i] >= g
  while (lo < hi) {
    int mid = (lo + hi) >> 1;
    if (batch[mid] < g) lo = mid + 1; else hi = mid;
  }
  gstart[g] = lo;
}

// ----------------- dual skinny GEMM -----------------
// blockIdx.y == 0: hW  = act(h) @ W_rel            (goes to aggregation)
// blockIdx.y == 1: buf = act(h) @ W_root + b_rel   (root term + bias, agg adds onto it)
// 64 nodes x 64 cols per block, 256 threads, 4x4 register tile per thread.
template<int K, bool RELU>
__global__ __launch_bounds__(256) void gemm_half(const float* __restrict__ h,
    const float* __restrict__ Wrel, const float* __restrict__ Wroot,
    const float* __restrict__ brel,
    float* __restrict__ hW, float* __restrict__ buf) {
  constexpr int HP = K + 4;                   // pad -> 2-way (free) LDS banking
  __shared__ float hs[64 * HP];
  __shared__ float ws[64 * 64];               // one 64-row K-chunk of W
  const int t = threadIdx.x;
  const int row0 = blockIdx.x * 64;
  const bool root = (blockIdx.y != 0);
  const float* __restrict__ W = root ? Wroot : Wrel;

  // stage 64 x K tile of h (apply input ReLU here)
  for (int idx = t; idx < 64 * (K / 4); idx += 256) {
    int n = idx / (K / 4), kq = idx % (K / 4);
    int node = row0 + n;
    float4 v = make_float4(0.f, 0.f, 0.f, 0.f);
    if (node < NN) v = *(const float4*)&h[(size_t)node * K + kq * 4];
    if (RELU) {
      v.x = fmaxf(v.x, 0.f); v.y = fmaxf(v.y, 0.f);
      v.z = fmaxf(v.z, 0.f); v.w = fmaxf(v.w, 0.f);
    }
    *(float4*)&hs[n * HP + kq * 4] = v;
  }

  const int tx = t & 15, ty = t >> 4;
  const int c0 = tx * 4, n0 = ty * 4;
  float acc[4][4];
  #pragma unroll
  for (int i = 0; i < 4; ++i)
    #pragma unroll
    for (int j = 0; j < 4; ++j) acc[i][j] = 0.f;

  for (int kb = 0; kb < K; kb += 64) {
    __syncthreads();                          // also covers hs staging on 1st iter
    for (int idx = t; idx < 64 * 16; idx += 256) {
      int k = idx >> 4, cq = idx & 15;
      *(float4*)&ws[k * 64 + cq * 4] = *(const float4*)&W[(size_t)(kb + k) * 64 + cq * 4];
    }
    __syncthreads();
    for (int k = 0; k < 64; k += 4) {
      float4 hv[4], wv[4];
      #pragma unroll
      for (int i = 0; i < 4; ++i) hv[i] = *(const float4*)&hs[(n0 + i) * HP + kb + k];
      #pragma unroll
      for (int kk = 0; kk < 4; ++kk) wv[kk] = *(const float4*)&ws[(k + kk) * 64 + c0];
      #pragma unroll
      for (int kk = 0; kk < 4; ++kk) {
        #pragma unroll
        for (int i = 0; i < 4; ++i) {
          float a = ((const float*)&hv[i])[kk];
          acc[i][0] += a * wv[kk].x;
          acc[i][1] += a * wv[kk].y;
          acc[i][2] += a * wv[kk].z;
          acc[i][3] += a * wv[kk].w;
        }
      }
    }
  }

  float4 bb = make_float4(0.f, 0.f, 0.f, 0.f);
  if (root) bb = *(const float4*)&brel[c0];
  float* __restrict__ outp = root ? buf : hW;
  #pragma unroll
  for (int i = 0; i < 4; ++i) {
    int node = row0 + n0 + i;
    if (node >= NN) continue;
    float4 o = make_float4(acc[i][0] + bb.x, acc[i][1] + bb.y,
                           acc[i][2] + bb.z, acc[i][3] + bb.w);
    *(float4*)&outp[(size_t)node * 64 + c0] = o;
  }
}

// ----------------- CSR aggregation: buf[n] += sum_{e in CSR[n]} hW[src_e] --------
__global__ __launch_bounds__(256) void aggregate_kernel(const float* __restrict__ hW,
    const int* __restrict__ row_start, const int* __restrict__ ssrc,
    float* __restrict__ buf) {
  int tid = blockIdx.x * 256 + threadIdx.x;
  int node = tid >> 4, c = tid & 15;
  if (node >= NN) return;
  float4 acc = *(const float4*)&buf[(size_t)node * 64 + c * 4];
  int s0 = row_start[node], s1 = row_start[node + 1];
  for (int e = s0; e < s1; ++e) {
    int s = ssrc[e];
    float4 v = *(const float4*)&hW[(size_t)s * 64 + c * 4];
    acc.x += v.x; acc.y += v.y; acc.z += v.z; acc.w += v.w;
  }
  *(float4*)&buf[(size_t)node * 64 + c * 4] = acc;
}

// ----------------- fused mean-pool + MLP head: one block per graph -----------------
__global__ __launch_bounds__(256) void pool_head_kernel(const float* __restrict__ buf,
    const int* __restrict__ gstart,
    const float* __restrict__ Wfc1, const float* __restrict__ bfc1,
    const float* __restrict__ Wfc2, const float* __restrict__ bfc2,
    float* __restrict__ out) {
  __shared__ float ps[4][64];
  __shared__ float m[64];
  __shared__ float h1[32];
  const int g = blockIdx.x, t = threadIdx.x;
  const int c = t & 63, w = t >> 6;
  const int s0 = gstart[g], s1 = gstart[g + 1];
  float acc = 0.f;
  for (int i = s0 + w; i < s1; i += 4)
    acc += fmaxf(buf[(size_t)i * 64 + c], 0.f);
  ps[w][c] = acc;
  __syncthreads();
  if (t < 64) {
    float n = (float)(s1 - s0);
    m[t] = (ps[0][t] + ps[1][t] + ps[2][t] + ps[3][t]) / fmaxf(n, 1.0f);
  }
  __syncthreads();
  if (t < 32) {
    float a = bfc1[t];
    #pragma unroll
    for (int k = 0; k < 64; ++k) a += m[k] * Wfc1[k * 32 + t];
    h1[t] = fmaxf(a, 0.f);
  }
  __syncthreads();
  if (t == 0) {
    float o = bfc2[0];
    #pragma unroll
    for (int j = 0; j < 32; ++j) o += h1[j] * Wfc2[j];
    out[g] = o;
  }
}

extern "C" void kernel_launch(void* const* d_in, const int* in_sizes, int n_in,
                              void* d_out, int out_size, void* d_ws, size_t ws_size,
                              hipStream_t stream) {
  const float* x      = (const float*)d_in[0];
  const int*   ei     = (const int*)d_in[1];
  const int*   batch  = (const int*)d_in[2];
  const float* Wrel1  = (const float*)d_in[3];
  const float* brel1  = (const float*)d_in[4];
  const float* Wroot1 = (const float*)d_in[5];
  const float* Wrel2  = (const float*)d_in[6];
  const float* brel2  = (const float*)d_in[7];
  const float* Wroot2 = (const float*)d_in[8];
  const float* Wrel3  = (const float*)d_in[9];
  const float* brel3  = (const float*)d_in[10];
  const float* Wroot3 = (const float*)d_in[11];
  const float* Wfc1   = (const float*)d_in[12];
  const float* bfc1   = (const float*)d_in[13];
  const float* Wfc2   = (const float*)d_in[14];
  const float* bfc2   = (const float*)d_in[15];
  const int* src = ei;
  const int* dst = ei + NE;

  char* w = (char*)d_ws;
  auto alloc = [&](size_t bytes) -> char* {
    char* p = w; w += (bytes + 255) & ~(size_t)255; return p;
  };
  float* hW     = (float*)alloc((size_t)NN * 64 * 4);
  float* bufA   = (float*)alloc((size_t)NN * 64 * 4);
  float* bufB   = (float*)alloc((size_t)NN * 64 * 4);
  int*   deg    = (int*)alloc((size_t)NN * 4);
  int*   rs     = (int*)alloc((size_t)(NN + 1) * 4);
  int*   cur    = (int*)alloc((size_t)(NN + 1) * 4);
  int*   ssrc   = (int*)alloc((size_t)NE * 4);
  int*   gstart = (int*)alloc((size_t)(GRAPHS + 1) * 4);
  int*   partials = (int*)alloc((size_t)256 * 4);

  hipMemsetAsync(deg, 0, (size_t)NN * 4, stream);

  hist_kernel<<<NE / 256, 256, 0, stream>>>(dst, deg);
  reduce_kernel<<<NB, 256, 0, stream>>>(deg, partials);
  scan_partials_kernel<<<1, 256, 0, stream>>>(partials, rs);
  scan_write_kernel<<<NB, 256, 0, stream>>>(deg, partials, rs, cur);
  scatter_kernel<<<NE / 256, 256, 0, stream>>>(src, dst, cur, ssrc);
  bounds_kernel<<<(GRAPHS + 1 + 255) / 256, 256, 0, stream>>>(batch, gstart);

  dim3 ggrid((NN + 63) / 64, 2);
  const int agrid = (NN * 16 + 255) / 256;  // 3125

  gemm_half<128, false><<<ggrid, 256, 0, stream>>>(x, Wrel1, Wroot1, brel1, hW, bufA);
  aggregate_kernel<<<agrid, 256, 0, stream>>>(hW, rs, ssrc, bufA);

  gemm_half<64, true><<<ggrid, 256, 0, stream>>>(bufA, Wrel2, Wroot2, brel2, hW, bufB);
  aggregate_kernel<<<agrid, 256, 0, stream>>>(hW, rs, ssrc, bufB);

  gemm_half<64, true><<<ggrid, 256, 0, stream>>>(bufB, Wrel3, Wroot3, brel3, hW, bufA);
  aggregate_kernel<<<agrid, 256, 0, stream>>>(hW, rs, ssrc, bufA);

  pool_head_kernel<<<GRAPHS, 256, 0, stream>>>(bufA, gstart, Wfc1, bfc1, Wfc2, bfc2,
                                               (float*)d_out);
}

// Round 4
// 243.966 us; speedup vs baseline: 2.0421x; 1.2371x over previous
//
#include <hip/hip_runtime.h>
#include <cstdint>
#include <cstddef>

#define NN 50000
#define NE 800000
#define GRAPHS 512
#define NBK 782                               // ceil(50000/64) buckets of 64 nodes

// ============ hierarchical CSR build (bucket = 64 consecutive nodes) ============

// phase 1: global bucket counts via per-block LDS histogram
__global__ __launch_bounds__(256) void bcount_kernel(const int* __restrict__ dst,
                                                     int* __restrict__ bcnt) {
  __shared__ int hist[NBK];
  const int t = threadIdx.x;
  for (int b = t; b < NBK; b += 256) hist[b] = 0;
  __syncthreads();
  const int e0 = blockIdx.x * 2048;
  #pragma unroll
  for (int i = 0; i < 8; ++i) {
    int e = e0 + i * 256 + t;
    if (e < NE) atomicAdd(&hist[dst[e] >> 6], 1);
  }
  __syncthreads();
  for (int b = t; b < NBK; b += 256) {
    int c = hist[b];
    if (c) atomicAdd(&bcnt[b], c);
  }
}

// phase 2: exclusive scan of bucket counts -> bbase[0..NBK], init bcur
__global__ __launch_bounds__(1024) void bscan_kernel(const int* __restrict__ bcnt,
                                                     int* __restrict__ bbase,
                                                     int* __restrict__ bcur) {
  __shared__ int sd[1024];
  const int t = threadIdx.x;
  int v = (t < NBK) ? bcnt[t] : 0;
  sd[t] = v;
  __syncthreads();
  for (int off = 1; off < 1024; off <<= 1) {
    int u = (t >= off) ? sd[t - off] : 0;
    __syncthreads();
    sd[t] += u;
    __syncthreads();
  }
  if (t < NBK) { int ex = sd[t] - v; bbase[t] = ex; bcur[t] = ex; }
  if (t == NBK - 1) bbase[NBK] = sd[t];      // = NE
}

// phase 3: bin edges into buckets with grouped (low-amplification) writes
__global__ __launch_bounds__(256) void bin_kernel(const int* __restrict__ src,
                                                  const int* __restrict__ dst,
                                                  int* __restrict__ bcur,
                                                  uint2* __restrict__ ebuf) {
  __shared__ int hist[NBK];
  __shared__ int base[NBK];
  __shared__ int lcur[NBK];
  const int t = threadIdx.x;
  for (int b = t; b < NBK; b += 256) { hist[b] = 0; lcur[b] = 0; }
  __syncthreads();
  const int e0 = blockIdx.x * 4096;
  int s_reg[16], d_reg[16];
  #pragma unroll
  for (int i = 0; i < 16; ++i) {
    int e = e0 + i * 256 + t;
    if (e < NE) {
      s_reg[i] = src[e]; d_reg[i] = dst[e];
      atomicAdd(&hist[d_reg[i] >> 6], 1);
    } else d_reg[i] = -1;
  }
  __syncthreads();
  for (int b = t; b < NBK; b += 256) {
    int c = hist[b];
    if (c) base[b] = atomicAdd(&bcur[b], c);
  }
  __syncthreads();
  #pragma unroll
  for (int i = 0; i < 16; ++i) {
    if (d_reg[i] >= 0) {
      int b = d_reg[i] >> 6;
      int r = atomicAdd(&lcur[b], 1);
      ebuf[base[b] + r] = make_uint2((unsigned)s_reg[i], (unsigned)d_reg[i]);
    }
  }
}

// phase 4: per-bucket counting sort in LDS -> row_start + dst-sorted ssrc
__global__ __launch_bounds__(256) void bucket_csr_kernel(const uint2* __restrict__ ebuf,
                                                         const int* __restrict__ bbase,
                                                         int* __restrict__ row_start,
                                                         int* __restrict__ ssrc) {
  __shared__ int ehist[64];
  __shared__ int sd[64];
  __shared__ int ecur[64];
  const int t = threadIdx.x;
  const int b = blockIdx.x;
  const int n0 = b << 6;
  const int e0 = bbase[b], e1 = bbase[b + 1];
  if (t < 64) ehist[t] = 0;
  __syncthreads();
  for (int e = e0 + t; e < e1; e += 256)
    atomicAdd(&ehist[ebuf[e].y & 63], 1);
  __syncthreads();
  if (t < 64) sd[t] = ehist[t];
  __syncthreads();
  for (int off = 1; off < 64; off <<= 1) {
    int u = (t >= off && t < 64) ? sd[t - off] : 0;
    __syncthreads();
    if (t < 64) sd[t] += u;
    __syncthreads();
  }
  if (t < 64) {
    int ex = e0 + sd[t] - ehist[t];           // global exclusive start for node n0+t
    ecur[t] = ex;
    if (n0 + t <= NN) row_start[n0 + t] = ex;
  }
  __syncthreads();
  for (int e = e0 + t; e < e1; e += 256) {
    uint2 ed = ebuf[e];
    int r = atomicAdd(&ecur[ed.y & 63], 1);
    ssrc[r] = (int)ed.x;
  }
}

// ----------------- graph boundaries (batch is sorted) -----------------
__global__ __launch_bounds__(256) void bounds_kernel(const int* __restrict__ batch,
                                                     int* __restrict__ gstart) {
  int g = blockIdx.x * 256 + threadIdx.x;
  if (g > GRAPHS) return;
  int lo = 0, hi = NN;                        // lower_bound: first i with batch[i] >= g
  while (lo < hi) {
    int mid = (lo + hi) >> 1;
    if (batch[mid] < g) lo = mid + 1; else hi = mid;
  }
  gstart[g] = lo;
}

// ----------------- dual skinny GEMM -----------------
// blockIdx.y == 0: hW  = act(h) @ W_rel            (goes to aggregation)
// blockIdx.y == 1: buf = act(h) @ W_root + b_rel   (root term + bias, agg adds onto it)
template<int K, bool RELU>
__global__ __launch_bounds__(256) void gemm_half(const float* __restrict__ h,
    const float* __restrict__ Wrel, const float* __restrict__ Wroot,
    const float* __restrict__ brel,
    float* __restrict__ hW, float* __restrict__ buf) {
  constexpr int HP = K + 4;                   // pad -> 2-way (free) LDS banking
  __shared__ float hs[64 * HP];
  __shared__ float ws[64 * 64];               // one 64-row K-chunk of W
  const int t = threadIdx.x;
  const int row0 = blockIdx.x * 64;
  const bool root = (blockIdx.y != 0);
  const float* __restrict__ W = root ? Wroot : Wrel;

  // stage 64 x K tile of h (apply input ReLU here)
  for (int idx = t; idx < 64 * (K / 4); idx += 256) {
    int n = idx / (K / 4), kq = idx % (K / 4);
    int node = row0 + n;
    float4 v = make_float4(0.f, 0.f, 0.f, 0.f);
    if (node < NN) v = *(const float4*)&h[(size_t)node * K + kq * 4];
    if (RELU) {
      v.x = fmaxf(v.x, 0.f); v.y = fmaxf(v.y, 0.f);
      v.z = fmaxf(v.z, 0.f); v.w = fmaxf(v.w, 0.f);
    }
    *(float4*)&hs[n * HP + kq * 4] = v;
  }

  const int tx = t & 15, ty = t >> 4;
  const int c0 = tx * 4, n0 = ty * 4;
  float acc[4][4];
  #pragma unroll
  for (int i = 0; i < 4; ++i)
    #pragma unroll
    for (int j = 0; j < 4; ++j) acc[i][j] = 0.f;

  for (int kb = 0; kb < K; kb += 64) {
    __syncthreads();                          // also covers hs staging on 1st iter
    for (int idx = t; idx < 64 * 16; idx += 256) {
      int k = idx >> 4, cq = idx & 15;
      *(float4*)&ws[k * 64 + cq * 4] = *(const float4*)&W[(size_t)(kb + k) * 64 + cq * 4];
    }
    __syncthreads();
    for (int k = 0; k < 64; k += 4) {
      float4 hv[4], wv[4];
      #pragma unroll
      for (int i = 0; i < 4; ++i) hv[i] = *(const float4*)&hs[(n0 + i) * HP + kb + k];
      #pragma unroll
      for (int kk = 0; kk < 4; ++kk) wv[kk] = *(const float4*)&ws[(k + kk) * 64 + c0];
      #pragma unroll
      for (int kk = 0; kk < 4; ++kk) {
        #pragma unroll
        for (int i = 0; i < 4; ++i) {
          float a = ((const float*)&hv[i])[kk];
          acc[i][0] += a * wv[kk].x;
          acc[i][1] += a * wv[kk].y;
          acc[i][2] += a * wv[kk].z;
          acc[i][3] += a * wv[kk].w;
        }
      }
    }
  }

  float4 bb = make_float4(0.f, 0.f, 0.f, 0.f);
  if (root) bb = *(const float4*)&brel[c0];
  float* __restrict__ outp = root ? buf : hW;
  #pragma unroll
  for (int i = 0; i < 4; ++i) {
    int node = row0 + n0 + i;
    if (node >= NN) continue;
    float4 o = make_float4(acc[i][0] + bb.x, acc[i][1] + bb.y,
                           acc[i][2] + bb.z, acc[i][3] + bb.w);
    *(float4*)&outp[(size_t)node * 64 + c0] = o;
  }
}

// ----------------- CSR aggregation: buf[n] += sum_{e in CSR[n]} hW[src_e] --------
__global__ __launch_bounds__(256) void aggregate_kernel(const float* __restrict__ hW,
    const int* __restrict__ row_start, const int* __restrict__ ssrc,
    float* __restrict__ buf) {
  int tid = blockIdx.x * 256 + threadIdx.x;
  int node = tid >> 4, c = tid & 15;
  if (node >= NN) return;
  float4 acc = *(const float4*)&buf[(size_t)node * 64 + c * 4];
  int s0 = row_start[node], s1 = row_start[node + 1];
  for (int e = s0; e < s1; ++e) {
    int s = ssrc[e];
    float4 v = *(const float4*)&hW[(size_t)s * 64 + c * 4];
    acc.x += v.x; acc.y += v.y; acc.z += v.z; acc.w += v.w;
  }
  *(float4*)&buf[(size_t)node * 64 + c * 4] = acc;
}

// ----------------- fused mean-pool + MLP head: one block per graph -----------------
__global__ __launch_bounds__(256) void pool_head_kernel(const float* __restrict__ buf,
    const int* __restrict__ gstart,
    const float* __restrict__ Wfc1, const float* __restrict__ bfc1,
    const float* __restrict__ Wfc2, const float* __restrict__ bfc2,
    float* __restrict__ out) {
  __shared__ float ps[4][64];
  __shared__ float m[64];
  __shared__ float h1[32];
  const int g = blockIdx.x, t = threadIdx.x;
  const int c = t & 63, w = t >> 6;
  const int s0 = gstart[g], s1 = gstart[g + 1];
  float acc = 0.f;
  for (int i = s0 + w; i < s1; i += 4)
    acc += fmaxf(buf[(size_t)i * 64 + c], 0.f);
  ps[w][c] = acc;
  __syncthreads();
  if (t < 64) {
    float n = (float)(s1 - s0);
    m[t] = (ps[0][t] + ps[1][t] + ps[2][t] + ps[3][t]) / fmaxf(n, 1.0f);
  }
  __syncthreads();
  if (t < 32) {
    float a = bfc1[t];
    #pragma unroll
    for (int k = 0; k < 64; ++k) a += m[k] * Wfc1[k * 32 + t];
    h1[t] = fmaxf(a, 0.f);
  }
  __syncthreads();
  if (t == 0) {
    float o = bfc2[0];
    #pragma unroll
    for (int j = 0; j < 32; ++j) o += h1[j] * Wfc2[j];
    out[g] = o;
  }
}

extern "C" void kernel_launch(void* const* d_in, const int* in_sizes, int n_in,
                              void* d_out, int out_size, void* d_ws, size_t ws_size,
                              hipStream_t stream) {
  const float* x      = (const float*)d_in[0];
  const int*   ei     = (const int*)d_in[1];
  const int*   batch  = (const int*)d_in[2];
  const float* Wrel1  = (const float*)d_in[3];
  const float* brel1  = (const float*)d_in[4];
  const float* Wroot1 = (const float*)d_in[5];
  const float* Wrel2  = (const float*)d_in[6];
  const float* brel2  = (const float*)d_in[7];
  const float* Wroot2 = (const float*)d_in[8];
  const float* Wrel3  = (const float*)d_in[9];
  const float* brel3  = (const float*)d_in[10];
  const float* Wroot3 = (const float*)d_in[11];
  const float* Wfc1   = (const float*)d_in[12];
  const float* bfc1   = (const float*)d_in[13];
  const float* Wfc2   = (const float*)d_in[14];
  const float* bfc2   = (const float*)d_in[15];
  const int* src = ei;
  const int* dst = ei + NE;

  char* w = (char*)d_ws;
  auto alloc = [&](size_t bytes) -> char* {
    char* p = w; w += (bytes + 255) & ~(size_t)255; return p;
  };
  float* hW     = (float*)alloc((size_t)NN * 64 * 4);
  float* bufA   = (float*)alloc((size_t)NN * 64 * 4);
  float* bufB   = (float*)alloc((size_t)NN * 64 * 4);
  int*   rs     = (int*)alloc((size_t)(NN + 1) * 4);
  int*   ssrc   = (int*)alloc((size_t)NE * 4);
  int*   gstart = (int*)alloc((size_t)(GRAPHS + 1) * 4);
  int*   bcnt   = (int*)alloc((size_t)NBK * 4);
  int*   bbase  = (int*)alloc((size_t)(NBK + 1) * 4);
  int*   bcur   = (int*)alloc((size_t)NBK * 4);
  // ebuf aliases bufB: bufB is first written by gemm2, after bucket_csr is done
  uint2* ebuf   = (uint2*)bufB;

  hipMemsetAsync(bcnt, 0, (size_t)NBK * 4, stream);

  bcount_kernel<<<(NE + 2047) / 2048, 256, 0, stream>>>(dst, bcnt);
  bscan_kernel<<<1, 1024, 0, stream>>>(bcnt, bbase, bcur);
  bin_kernel<<<(NE + 4095) / 4096, 256, 0, stream>>>(src, dst, bcur, ebuf);
  bucket_csr_kernel<<<NBK, 256, 0, stream>>>(ebuf, bbase, rs, ssrc);
  bounds_kernel<<<(GRAPHS + 1 + 255) / 256, 256, 0, stream>>>(batch, gstart);

  dim3 ggrid((NN + 63) / 64, 2);
  const int agrid = (NN * 16 + 255) / 256;  // 3125

  gemm_half<128, false><<<ggrid, 256, 0, stream>>>(x, Wrel1, Wroot1, brel1, hW, bufA);
  aggregate_kernel<<<agrid, 256, 0, stream>>>(hW, rs, ssrc, bufA);

  gemm_half<64, true><<<ggrid, 256, 0, stream>>>(bufA, Wrel2, Wroot2, brel2, hW, bufB);
  aggregate_kernel<<<agrid, 256, 0, stream>>>(hW, rs, ssrc, bufB);

  gemm_half<64, true><<<ggrid, 256, 0, stream>>>(bufB, Wrel3, Wroot3, brel3, hW, bufA);
  aggregate_kernel<<<agrid, 256, 0, stream>>>(hW, rs, ssrc, bufA);

  pool_head_kernel<<<GRAPHS, 256, 0, stream>>>(bufA, gstart, Wfc1, bfc1, Wfc2, bfc2,
                                               (float*)d_out);
}

// Round 5
// 205.235 us; speedup vs baseline: 2.4275x; 1.1887x over previous
//
#include <hip/hip_runtime.h>
#include <cstdint>
#include <cstddef>

#define NN 50000
#define NE 800000
#define GRAPHS 512
#define NBK 782                               // ceil(50000/64) buckets of 64 nodes

typedef __attribute__((ext_vector_type(8))) short bf16x8;
typedef __attribute__((ext_vector_type(4))) float f32x4;

__device__ __forceinline__ unsigned short f2bf(float f) {
  union { float f; unsigned u; } v; v.f = f;
  unsigned r = v.u + 0x7FFF + ((v.u >> 16) & 1);   // RNE
  return (unsigned short)(r >> 16);
}
__device__ __forceinline__ float bf2f(unsigned short h) {
  union { unsigned u; float f; } v; v.u = ((unsigned)h) << 16;
  return v.f;
}

__global__ __launch_bounds__(256) void zero_kernel(int* __restrict__ p, int n) {
  int i = blockIdx.x * 256 + threadIdx.x;
  if (i < n) p[i] = 0;
}

// ============ hierarchical CSR build (bucket = 64 consecutive nodes) ============

__global__ __launch_bounds__(256) void bcount_kernel(const int* __restrict__ dst,
                                                     int* __restrict__ bcnt) {
  __shared__ int hist[NBK];
  const int t = threadIdx.x;
  for (int b = t; b < NBK; b += 256) hist[b] = 0;
  __syncthreads();
  const int e0 = blockIdx.x * 2048;
  #pragma unroll
  for (int i = 0; i < 8; ++i) {
    int e = e0 + i * 256 + t;
    if (e < NE) atomicAdd(&hist[dst[e] >> 6], 1);
  }
  __syncthreads();
  for (int b = t; b < NBK; b += 256) {
    int c = hist[b];
    if (c) atomicAdd(&bcnt[b], c);
  }
}

__global__ __launch_bounds__(1024) void bscan_kernel(const int* __restrict__ bcnt,
                                                     int* __restrict__ bbase,
                                                     int* __restrict__ bcur) {
  __shared__ int sd[1024];
  const int t = threadIdx.x;
  int v = (t < NBK) ? bcnt[t] : 0;
  sd[t] = v;
  __syncthreads();
  for (int off = 1; off < 1024; off <<= 1) {
    int u = (t >= off) ? sd[t - off] : 0;
    __syncthreads();
    sd[t] += u;
    __syncthreads();
  }
  if (t < NBK) { int ex = sd[t] - v; bbase[t] = ex; bcur[t] = ex; }
  if (t == NBK - 1) bbase[NBK] = sd[t];      // = NE
}

__global__ __launch_bounds__(256) void bin_kernel(const int* __restrict__ src,
                                                  const int* __restrict__ dst,
                                                  int* __restrict__ bcur,
                                                  uint2* __restrict__ ebuf) {
  __shared__ int hist[NBK];
  __shared__ int base[NBK];
  __shared__ int lcur[NBK];
  const int t = threadIdx.x;
  for (int b = t; b < NBK; b += 256) { hist[b] = 0; lcur[b] = 0; }
  __syncthreads();
  const int e0 = blockIdx.x * 4096;
  int s_reg[16], d_reg[16];
  #pragma unroll
  for (int i = 0; i < 16; ++i) {
    int e = e0 + i * 256 + t;
    if (e < NE) {
      s_reg[i] = src[e]; d_reg[i] = dst[e];
      atomicAdd(&hist[d_reg[i] >> 6], 1);
    } else d_reg[i] = -1;
  }
  __syncthreads();
  for (int b = t; b < NBK; b += 256) {
    int c = hist[b];
    if (c) base[b] = atomicAdd(&bcur[b], c);
  }
  __syncthreads();
  #pragma unroll
  for (int i = 0; i < 16; ++i) {
    if (d_reg[i] >= 0) {
      int b = d_reg[i] >> 6;
      int r = atomicAdd(&lcur[b], 1);
      ebuf[base[b] + r] = make_uint2((unsigned)s_reg[i], (unsigned)d_reg[i]);
    }
  }
}

__global__ __launch_bounds__(256) void bucket_csr_kernel(const uint2* __restrict__ ebuf,
                                                         const int* __restrict__ bbase,
                                                         int* __restrict__ row_start,
                                                         int* __restrict__ ssrc) {
  __shared__ int ehist[64];
  __shared__ int sd[64];
  __shared__ int ecur[64];
  const int t = threadIdx.x;
  const int b = blockIdx.x;
  const int n0 = b << 6;
  const int e0 = bbase[b], e1 = bbase[b + 1];
  if (t < 64) ehist[t] = 0;
  __syncthreads();
  for (int e = e0 + t; e < e1; e += 256)
    atomicAdd(&ehist[ebuf[e].y & 63], 1);
  __syncthreads();
  if (t < 64) sd[t] = ehist[t];
  __syncthreads();
  for (int off = 1; off < 64; off <<= 1) {
    int u = (t >= off && t < 64) ? sd[t - off] : 0;
    __syncthreads();
    if (t < 64) sd[t] += u;
    __syncthreads();
  }
  if (t < 64) {
    int ex = e0 + sd[t] - ehist[t];
    ecur[t] = ex;
    if (n0 + t <= NN) row_start[n0 + t] = ex;
  }
  __syncthreads();
  for (int e = e0 + t; e < e1; e += 256) {
    uint2 ed = ebuf[e];
    int r = atomicAdd(&ecur[ed.y & 63], 1);
    ssrc[r] = (int)ed.x;
  }
}

// ----------------- graph boundaries (batch is sorted) -----------------
__global__ __launch_bounds__(256) void bounds_kernel(const int* __restrict__ batch,
                                                     int* __restrict__ gstart) {
  int g = blockIdx.x * 256 + threadIdx.x;
  if (g > GRAPHS) return;
  int lo = 0, hi = NN;
  while (lo < hi) {
    int mid = (lo + hi) >> 1;
    if (batch[mid] < g) lo = mid + 1; else hi = mid;
  }
  gstart[g] = lo;
}

// ----------------- weight prep: transpose + cast to bf16, [col][k] -----------------
__global__ __launch_bounds__(256) void prep_w_kernel(
    const float* __restrict__ Wrel1, const float* __restrict__ Wroot1,
    const float* __restrict__ Wrel2, const float* __restrict__ Wroot2,
    const float* __restrict__ Wrel3, const float* __restrict__ Wroot3,
    unsigned short* __restrict__ Wt1, unsigned short* __restrict__ Wt2,
    unsigned short* __restrict__ Wt3) {
  int tid = blockIdx.x * 256 + threadIdx.x;
  int stride = gridDim.x * 256;
  for (int idx = tid; idx < 128 * 128; idx += stride) {
    int c = idx >> 7, k = idx & 127;
    Wt1[c * 128 + k] = f2bf(c < 64 ? Wrel1[k * 64 + c] : Wroot1[k * 64 + (c - 64)]);
  }
  for (int idx = tid; idx < 128 * 64; idx += stride) {
    int c = idx >> 6, k = idx & 63;
    Wt2[c * 64 + k] = f2bf(c < 64 ? Wrel2[k * 64 + c] : Wroot2[k * 64 + (c - 64)]);
    Wt3[c * 64 + k] = f2bf(c < 64 ? Wrel3[k * 64 + c] : Wroot3[k * 64 + (c - 64)]);
  }
}

// ----------------- fused MFMA GEMM: [hW | buf] = act(h) @ [Wrel | Wroot] ------------
// BM=64, BN=128, 4 waves; wave w owns rows [w*16, w*16+16) x all 128 cols.
// LDS XOR-swizzle ((row&7)<<3 in shorts) keeps ds_read_b128 conflict-free.
template<int K, bool RELU>
__global__ __launch_bounds__(256) void gemm_mfma(const float* __restrict__ h,
    const unsigned short* __restrict__ Wt,    // [128][K] bf16 (pre-transposed)
    const float* __restrict__ brel,
    unsigned short* __restrict__ hW,          // [NN][64] bf16 (rel result)
    float* __restrict__ buf) {                // [NN][64] f32  (root + bias)
  __shared__ __align__(16) unsigned short as[64 * K];
  __shared__ __align__(16) unsigned short bs[128 * K];
  constexpr int SEG = K / 8;
  const int t = threadIdx.x;
  const int row0 = blockIdx.x * 64;

  // stage A: 64 x K tile of h, relu + cast, swizzled
  for (int idx = t; idx < 64 * SEG; idx += 256) {
    int r = idx / SEG, kq = idx % SEG;
    int node = row0 + r;
    float4 v0 = make_float4(0.f, 0.f, 0.f, 0.f), v1 = v0;
    if (node < NN) {
      const float* p = &h[(size_t)node * K + kq * 8];
      v0 = *(const float4*)p; v1 = *(const float4*)(p + 4);
    }
    if (RELU) {
      v0.x = fmaxf(v0.x, 0.f); v0.y = fmaxf(v0.y, 0.f);
      v0.z = fmaxf(v0.z, 0.f); v0.w = fmaxf(v0.w, 0.f);
      v1.x = fmaxf(v1.x, 0.f); v1.y = fmaxf(v1.y, 0.f);
      v1.z = fmaxf(v1.z, 0.f); v1.w = fmaxf(v1.w, 0.f);
    }
    uint4 p;
    p.x = f2bf(v0.x) | ((unsigned)f2bf(v0.y) << 16);
    p.y = f2bf(v0.z) | ((unsigned)f2bf(v0.w) << 16);
    p.z = f2bf(v1.x) | ((unsigned)f2bf(v1.y) << 16);
    p.w = f2bf(v1.z) | ((unsigned)f2bf(v1.w) << 16);
    int sidx = (r * K + kq * 8) ^ ((r & 7) << 3);
    *(uint4*)&as[sidx] = p;
  }
  // stage B: 128 cols x K, already bf16 [col][k], swizzled
  for (int idx = t; idx < 128 * SEG; idx += 256) {
    int c = idx / SEG, kq = idx % SEG;
    uint4 v = *(const uint4*)&Wt[c * K + kq * 8];
    int sidx = (c * K + kq * 8) ^ ((c & 7) << 3);
    *(uint4*)&bs[sidx] = v;
  }
  __syncthreads();

  const int lane = t & 63, wave = t >> 6;
  const int li = lane & 15;                   // A-row / B-col / D-col within 16
  const int kg = (lane >> 4) * 8;             // k-group offset
  const int ar = wave * 16 + li;
  f32x4 acc[8];
  #pragma unroll
  for (int i = 0; i < 8; ++i) acc[i] = (f32x4){0.f, 0.f, 0.f, 0.f};

  #pragma unroll
  for (int k0 = 0; k0 < K; k0 += 32) {
    int ka = k0 + kg;
    bf16x8 a = *(bf16x8*)&as[(ar * K + ka) ^ ((ar & 7) << 3)];
    #pragma unroll
    for (int nb = 0; nb < 8; ++nb) {
      int bc = nb * 16 + li;
      bf16x8 b = *(bf16x8*)&bs[(bc * K + ka) ^ ((bc & 7) << 3)];
      acc[nb] = __builtin_amdgcn_mfma_f32_16x16x32_bf16(a, b, acc[nb], 0, 0, 0);
    }
  }

  // D layout: col = lane&15, row = (lane>>4)*4 + reg  [m89-verified]
  const int orow = row0 + wave * 16 + (lane >> 4) * 4;
  #pragma unroll
  for (int nb = 0; nb < 4; ++nb) {            // rel half -> hW (bf16)
    #pragma unroll
    for (int r = 0; r < 4; ++r) {
      int node = orow + r;
      if (node < NN) hW[(size_t)node * 64 + nb * 16 + li] = f2bf(acc[nb][r]);
    }
  }
  #pragma unroll
  for (int nb = 4; nb < 8; ++nb) {            // root half -> buf (f32, + bias)
    float bb = brel[(nb - 4) * 16 + li];
    #pragma unroll
    for (int r = 0; r < 4; ++r) {
      int node = orow + r;
      if (node < NN) buf[(size_t)node * 64 + (nb - 4) * 16 + li] = acc[nb][r] + bb;
    }
  }
}

// ----------------- CSR aggregation: buf[n] += sum hW[src] (bf16 gather) -----------
__global__ __launch_bounds__(256) void aggregate_kernel(
    const unsigned short* __restrict__ hW,
    const int* __restrict__ row_start, const int* __restrict__ ssrc,
    float* __restrict__ buf) {
  int tid = blockIdx.x * 256 + threadIdx.x;
  int node = tid >> 4, c = tid & 15;
  if (node >= NN) return;
  float4 acc = *(const float4*)&buf[(size_t)node * 64 + c * 4];
  int s0 = row_start[node], s1 = row_start[node + 1];
  for (int e = s0; e < s1; ++e) {
    int s = ssrc[e];
    ushort4 v = *(const ushort4*)&hW[(size_t)s * 64 + c * 4];
    acc.x += bf2f(v.x); acc.y += bf2f(v.y);
    acc.z += bf2f(v.z); acc.w += bf2f(v.w);
  }
  *(float4*)&buf[(size_t)node * 64 + c * 4] = acc;
}

// ----------------- fused mean-pool + MLP head: one block per graph -----------------
__global__ __launch_bounds__(256) void pool_head_kernel(const float* __restrict__ buf,
    const int* __restrict__ gstart,
    const float* __restrict__ Wfc1, const float* __restrict__ bfc1,
    const float* __restrict__ Wfc2, const float* __restrict__ bfc2,
    float* __restrict__ out) {
  __shared__ float ps[4][64];
  __shared__ float m[64];
  __shared__ float h1[32];
  const int g = blockIdx.x, t = threadIdx.x;
  const int c = t & 63, w = t >> 6;
  const int s0 = gstart[g], s1 = gstart[g + 1];
  float acc = 0.f;
  for (int i = s0 + w; i < s1; i += 4)
    acc += fmaxf(buf[(size_t)i * 64 + c], 0.f);
  ps[w][c] = acc;
  __syncthreads();
  if (t < 64) {
    float n = (float)(s1 - s0);
    m[t] = (ps[0][t] + ps[1][t] + ps[2][t] + ps[3][t]) / fmaxf(n, 1.0f);
  }
  __syncthreads();
  if (t < 32) {
    float a = bfc1[t];
    #pragma unroll
    for (int k = 0; k < 64; ++k) a += m[k] * Wfc1[k * 32 + t];
    h1[t] = fmaxf(a, 0.f);
  }
  __syncthreads();
  if (t == 0) {
    float o = bfc2[0];
    #pragma unroll
    for (int j = 0; j < 32; ++j) o += h1[j] * Wfc2[j];
    out[g] = o;
  }
}

extern "C" void kernel_launch(void* const* d_in, const int* in_sizes, int n_in,
                              void* d_out, int out_size, void* d_ws, size_t ws_size,
                              hipStream_t stream) {
  const float* x      = (const float*)d_in[0];
  const int*   ei     = (const int*)d_in[1];
  const int*   batch  = (const int*)d_in[2];
  const float* Wrel1  = (const float*)d_in[3];
  const float* brel1  = (const float*)d_in[4];
  const float* Wroot1 = (const float*)d_in[5];
  const float* Wrel2  = (const float*)d_in[6];
  const float* brel2  = (const float*)d_in[7];
  const float* Wroot2 = (const float*)d_in[8];
  const float* Wrel3  = (const float*)d_in[9];
  const float* brel3  = (const float*)d_in[10];
  const float* Wroot3 = (const float*)d_in[11];
  const float* Wfc1   = (const float*)d_in[12];
  const float* bfc1   = (const float*)d_in[13];
  const float* Wfc2   = (const float*)d_in[14];
  const float* bfc2   = (const float*)d_in[15];
  const int* src = ei;
  const int* dst = ei + NE;

  char* w = (char*)d_ws;
  auto alloc = [&](size_t bytes) -> char* {
    char* p = w; w += (bytes + 255) & ~(size_t)255; return p;
  };
  unsigned short* hW = (unsigned short*)alloc((size_t)NN * 64 * 2);   // bf16
  float* bufA   = (float*)alloc((size_t)NN * 64 * 4);
  float* bufB   = (float*)alloc((size_t)NN * 64 * 4);
  int*   rs     = (int*)alloc((size_t)(NN + 1) * 4);
  int*   ssrc   = (int*)alloc((size_t)NE * 4);
  int*   gstart = (int*)alloc((size_t)(GRAPHS + 1) * 4);
  int*   bcnt   = (int*)alloc((size_t)NBK * 4);
  int*   bbase  = (int*)alloc((size_t)(NBK + 1) * 4);
  int*   bcur   = (int*)alloc((size_t)NBK * 4);
  unsigned short* Wt1 = (unsigned short*)alloc((size_t)128 * 128 * 2);
  unsigned short* Wt2 = (unsigned short*)alloc((size_t)128 * 64 * 2);
  unsigned short* Wt3 = (unsigned short*)alloc((size_t)128 * 64 * 2);
  // ebuf aliases bufB: bufB is first written by gemm2, after bucket_csr is done
  uint2* ebuf   = (uint2*)bufB;

  zero_kernel<<<(NBK + 255) / 256, 256, 0, stream>>>(bcnt, NBK);
  bcount_kernel<<<(NE + 2047) / 2048, 256, 0, stream>>>(dst, bcnt);
  bscan_kernel<<<1, 1024, 0, stream>>>(bcnt, bbase, bcur);
  bin_kernel<<<(NE + 4095) / 4096, 256, 0, stream>>>(src, dst, bcur, ebuf);
  bucket_csr_kernel<<<NBK, 256, 0, stream>>>(ebuf, bbase, rs, ssrc);
  bounds_kernel<<<(GRAPHS + 1 + 255) / 256, 256, 0, stream>>>(batch, gstart);
  prep_w_kernel<<<32, 256, 0, stream>>>(Wrel1, Wroot1, Wrel2, Wroot2, Wrel3, Wroot3,
                                        Wt1, Wt2, Wt3);

  const int ggrid = (NN + 63) / 64;          // 782
  const int agrid = (NN * 16 + 255) / 256;   // 3125

  gemm_mfma<128, false><<<ggrid, 256, 0, stream>>>(x, Wt1, brel1, hW, bufA);
  aggregate_kernel<<<agrid, 256, 0, stream>>>(hW, rs, ssrc, bufA);

  gemm_mfma<64, true><<<ggrid, 256, 0, stream>>>(bufA, Wt2, brel2, hW, bufB);
  aggregate_kernel<<<agrid, 256, 0, stream>>>(hW, rs, ssrc, bufB);

  gemm_mfma<64, true><<<ggrid, 256, 0, stream>>>(bufB, Wt3, brel3, hW, bufA);
  aggregate_kernel<<<agrid, 256, 0, stream>>>(hW, rs, ssrc, bufA);

  pool_head_kernel<<<GRAPHS, 256, 0, stream>>>(bufA, gstart, Wfc1, bfc1, Wfc2, bfc2,
                                               (float*)d_out);
}